// Round 1
// baseline (252.936 us; speedup 1.0000x reference)
//
#include <hip/hip_runtime.h>
#include <math.h>
#include <stdint.h>

// ---------------------------------------------------------------------------
// softmax(x @ x^T) @ x   for x[B=8][S=2048][D=512] fp32.
// Flash-style online softmax, bf16 MFMA (16x16x32), fp32 accumulation.
// Pass 1 converts x to bf16 twice into d_ws: row-major xb (Q/K) and
// d-major xbt (V), so every MFMA fragment read is a contiguous 16B load.
// ---------------------------------------------------------------------------

#define B_ 8
#define S_ 2048
#define D_ 512

typedef __attribute__((ext_vector_type(8))) short   short8;   // 8 x bf16 frag
typedef __attribute__((ext_vector_type(4))) float   f32x4;
typedef __attribute__((ext_vector_type(4))) unsigned int u32x4;
typedef __attribute__((ext_vector_type(2))) unsigned int u32x2;

__device__ __forceinline__ unsigned short f2bf(float f) {
  unsigned u = __float_as_uint(f);
  u += 0x7fffu + ((u >> 16) & 1u);   // round-to-nearest-even
  return (unsigned short)(u >> 16);
}

__device__ __forceinline__ void async16(const void* src, void* dst) {
  // global -> LDS direct, 16B per lane; LDS dest = wave-uniform base + lane*16
  __builtin_amdgcn_global_load_lds(
      (const __attribute__((address_space(1))) void*)src,
      (__attribute__((address_space(3))) void*)dst, 16, 0, 0);
}

// ---------------------------------------------------------------------------
// Kernel 1: fp32 -> bf16 convert + transpose.
// grid: 8 batches * 32 s-tiles * 8 d-tiles = 2048 blocks of 256 threads,
// each handles a 64(s) x 64(d) tile through LDS.
// ---------------------------------------------------------------------------
__global__ __launch_bounds__(256) void cvt_kernel(
    const float* __restrict__ x,
    unsigned short* __restrict__ xb,    // [B][S][D] bf16
    unsigned short* __restrict__ xbt) { // [B][D][S] bf16
  __shared__ unsigned short T[64][68];  // +4 pad to break bank alignment

  const int blk = blockIdx.x;
  const int b   = blk >> 8;
  const int rem = blk & 255;
  const int s0  = (rem >> 3) * 64;
  const int d0  = (rem & 7) * 64;
  const int t   = threadIdx.x;
  const int tr  = t >> 4;        // 0..15
  const int tc  = (t & 15) * 4;  // 0..60

#pragma unroll
  for (int i = 0; i < 4; ++i) {
    int sl = i * 16 + tr;
    size_t idx = (size_t)(b * S_ + s0 + sl) * D_ + d0 + tc;
    f32x4 v = *(const f32x4*)(x + idx);
    unsigned short h0 = f2bf(v.x), h1 = f2bf(v.y), h2 = f2bf(v.z), h3 = f2bf(v.w);
    u32x2 pk;
    pk.x = (unsigned)h0 | ((unsigned)h1 << 16);
    pk.y = (unsigned)h2 | ((unsigned)h3 << 16);
    *(u32x2*)(xb + idx) = pk;
    *(u32x2*)(&T[sl][tc]) = pk;
  }
  __syncthreads();
#pragma unroll
  for (int i = 0; i < 4; ++i) {
    int dl = i * 16 + tr;   // d within tile
    int sl = tc;            // s within tile (4 consecutive)
    unsigned short a0 = T[sl + 0][dl];
    unsigned short a1 = T[sl + 1][dl];
    unsigned short a2 = T[sl + 2][dl];
    unsigned short a3 = T[sl + 3][dl];
    u32x2 pk;
    pk.x = (unsigned)a0 | ((unsigned)a1 << 16);
    pk.y = (unsigned)a2 | ((unsigned)a3 << 16);
    *(u32x2*)(xbt + (size_t)(b * D_ + d0 + dl) * S_ + s0 + sl) = pk;
  }
}

// ---------------------------------------------------------------------------
// Kernel 2: flash attention.
// 256 blocks (batch = blockIdx&7 -> XCD-pinned; 32 q-tiles of 64 rows).
// 4 waves/block, wave owns 16 q-rows: O[16][512] fp32 = 128 VGPR/lane,
// Q frags 64 VGPR/lane. TK=64 keys/tile.
// LDS: K[64][520] (rows padded +16B -> uniform 8-phase b128 reads)
//      Vt[512][72] (d-major, rows padded)
//      P[4][16][72] per-wave C->A layout round-trip.
// ---------------------------------------------------------------------------
#define TKK   64
#define KROW  520                       // ushorts per K LDS row
#define VROW  72                        // ushorts per Vt LDS row
#define PROW  72
#define VT_OFF (64 * KROW)              // 33280
#define PL_OFF (VT_OFF + 512 * VROW)    // 70144
#define LDS_US (PL_OFF + 4 * 16 * PROW) // 74752 ushorts = 149504 B

__global__ __launch_bounds__(256, 1) void attn_kernel(
    const unsigned short* __restrict__ xb,
    const unsigned short* __restrict__ xbt,
    float* __restrict__ out) {
  extern __shared__ unsigned short lds[];
  unsigned short* KL = lds;            // [64][KROW]
  unsigned short* VT = lds + VT_OFF;   // [512][VROW]
  unsigned short* PL = lds + PL_OFF;   // [4][16][PROW]

  const int b    = blockIdx.x & 7;
  const int qt   = blockIdx.x >> 3;
  const int tid  = threadIdx.x;
  const int wave = tid >> 6;
  const int lane = tid & 63;
  const int quad = lane >> 4;
  const int l16  = lane & 15;

  const int q0 = qt * 64 + wave * 16;  // wave's first q row
  const unsigned short* xbB  = xb  + (size_t)b * S_ * D_;
  const unsigned short* xbtB = xbt + (size_t)b * D_ * S_;

  // Q fragments: A-layout, lane holds Q[q0 + l16][dc*32 + quad*8 + j]
  short8 Qf[16];
#pragma unroll
  for (int dc = 0; dc < 16; ++dc)
    Qf[dc] = *(const short8*)(xbB + (size_t)(q0 + l16) * D_ + dc * 32 + quad * 8);

  f32x4 O[32];
#pragma unroll
  for (int i = 0; i < 32; ++i) O[i] = (f32x4)(0.0f);
  float m4[4] = {-INFINITY, -INFINITY, -INFINITY, -INFINITY};
  float l4[4] = {0.f, 0.f, 0.f, 0.f};

  unsigned short* PLw = PL + wave * 16 * PROW;

#pragma unroll 1
  for (int kt = 0; kt < S_ / TKK; ++kt) {
    const int k0 = kt * TKK;
    __syncthreads();  // previous tile fully consumed

    // --- stage K tile (row-major): one global_load_lds per 1KB row ---
#pragma unroll
    for (int i = 0; i < 16; ++i) {
      int r = wave * 16 + i;  // wave-uniform
      async16(xbB + (size_t)(k0 + r) * D_ + lane * 8, KL + r * KROW);
    }
    // --- stage Vt tile (d-major) via registers (rows padded to 144B) ---
#pragma unroll
    for (int i = 0; i < 16; ++i) {
      int d  = i * 32 + (tid >> 3);
      int kc = (tid & 7) * 8;
      u32x4 v = *(const u32x4*)(xbtB + (size_t)d * S_ + k0 + kc);
      *(u32x4*)(VT + d * VROW + kc) = v;
    }
    __syncthreads();  // drains vmcnt (async K) + lgkmcnt (Vt writes)

    // --- S = Q K^T  (16q x 64k), fp32 accum ---
    f32x4 Sc[4];
#pragma unroll
    for (int nt = 0; nt < 4; ++nt) Sc[nt] = (f32x4)(0.0f);
#pragma unroll
    for (int dc = 0; dc < 16; ++dc) {
#pragma unroll
      for (int nt = 0; nt < 4; ++nt) {
        short8 Kf = *(const short8*)(KL + (nt * 16 + l16) * KROW + dc * 32 + quad * 8);
        Sc[nt] = __builtin_amdgcn_mfma_f32_16x16x32_bf16(Qf[dc], Kf, Sc[nt], 0, 0, 0);
      }
    }

    // --- online softmax (rows = quad*4 + r, cols across l16 x nt) ---
    float alpha[4];
    bool need = false;
#pragma unroll
    for (int r = 0; r < 4; ++r) {
      float v = fmaxf(fmaxf(Sc[0][r], Sc[1][r]), fmaxf(Sc[2][r], Sc[3][r]));
      v = fmaxf(v, __shfl_xor(v, 1));
      v = fmaxf(v, __shfl_xor(v, 2));
      v = fmaxf(v, __shfl_xor(v, 4));
      v = fmaxf(v, __shfl_xor(v, 8));
      need = need || (v > m4[r]);
      float mi = fmaxf(m4[r], v);
      alpha[r] = __expf(m4[r] - mi);  // ==1.0 when max unchanged
      m4[r] = mi;
    }
#pragma unroll
    for (int nt = 0; nt < 4; ++nt)
#pragma unroll
      for (int r = 0; r < 4; ++r)
        Sc[nt][r] = __expf(Sc[nt][r] - m4[r]);
#pragma unroll
    for (int r = 0; r < 4; ++r) {
      float s = Sc[0][r] + Sc[1][r] + Sc[2][r] + Sc[3][r];
      s += __shfl_xor(s, 1);
      s += __shfl_xor(s, 2);
      s += __shfl_xor(s, 4);
      s += __shfl_xor(s, 8);
      l4[r] = l4[r] * alpha[r] + s;
    }
    // O rescale happens only in the tile containing the diagonal (~1/32)
    if (__any(need)) {
#pragma unroll
      for (int nt2 = 0; nt2 < 32; ++nt2)
#pragma unroll
        for (int r = 0; r < 4; ++r) O[nt2][r] *= alpha[r];
    }

    // --- P: C-layout -> A-layout via per-wave LDS (no barrier needed) ---
#pragma unroll
    for (int nt = 0; nt < 4; ++nt)
#pragma unroll
      for (int r = 0; r < 4; ++r)
        PLw[(quad * 4 + r) * PROW + nt * 16 + l16] = f2bf(Sc[nt][r]);

    // --- O += P V  (16q x 512d) ---
#pragma unroll
    for (int kb = 0; kb < 2; ++kb) {
      short8 Pf = *(const short8*)(PLw + l16 * PROW + kb * 32 + quad * 8);
#pragma unroll
      for (int nt2 = 0; nt2 < 32; ++nt2) {
        short8 Vf = *(const short8*)(VT + (nt2 * 16 + l16) * VROW + kb * 32 + quad * 8);
        O[nt2] = __builtin_amdgcn_mfma_f32_16x16x32_bf16(Pf, Vf, O[nt2], 0, 0, 0);
      }
    }
  }

  // --- epilogue: O / l ---
  float inv[4];
#pragma unroll
  for (int r = 0; r < 4; ++r) inv[r] = 1.0f / l4[r];
  float* outB = out + (size_t)b * S_ * D_;
#pragma unroll
  for (int nt2 = 0; nt2 < 32; ++nt2)
#pragma unroll
    for (int r = 0; r < 4; ++r)
      outB[(size_t)(q0 + quad * 4 + r) * D_ + nt2 * 16 + l16] = O[nt2][r] * inv[r];
}

// ---------------------------------------------------------------------------
extern "C" void kernel_launch(void* const* d_in, const int* in_sizes, int n_in,
                              void* d_out, int out_size, void* d_ws, size_t ws_size,
                              hipStream_t stream) {
  const float* x = (const float*)d_in[0];
  float* out = (float*)d_out;
  unsigned short* xb  = (unsigned short*)d_ws;                  // 16.78 MB
  unsigned short* xbt = xb + (size_t)B_ * S_ * D_;              // 16.78 MB

  cvt_kernel<<<2048, 256, 0, stream>>>(x, xb, xbt);

  hipFuncSetAttribute((const void*)attn_kernel,
                      hipFuncAttributeMaxDynamicSharedMemorySize, LDS_US * 2);
  attn_kernel<<<256, 256, LDS_US * 2, stream>>>(xb, xbt, out);
}